// Round 4
// baseline (589.520 us; speedup 1.0000x reference)
//
#include <hip/hip_runtime.h>
#include <stdint.h>

#define LOG2F 0.693147180559945f

typedef __attribute__((ext_vector_type(8))) short short8;
typedef __attribute__((ext_vector_type(4))) float f32x4;

// shifted softplus: softplus(x) - log(2), stable form
__device__ __forceinline__ float ssp(float x){
  float t = __expf(-fabsf(x));
  return fmaxf(x, 0.0f) + __logf(1.0f + t) - LOG2F;
}

// fp32 -> bf16 round-to-nearest-even (16-bit pattern in low bits)
__device__ __forceinline__ uint32_t bf16rn(float x){
  uint32_t u = __float_as_uint(x);
  return (u + 0x7fffu + ((u >> 16) & 1u)) >> 16;
}
// split x ~= hi + lo (both bf16). hi RNE, lo = RNE(x - hi): ~16 mantissa bits kept.
__device__ __forceinline__ void split2(float x, unsigned short &h, unsigned short &l){
  uint32_t hb = bf16rn(x);
  h = (unsigned short)hb;
  float hf = __uint_as_float(hb << 16);
  l = (unsigned short)bf16rn(x - hf);
}

// ============================================================================
// MFMA fragment packing (mfma_f32_16x16x32_bf16) — HW-validated in round 2:
//   A-frag: lane l, elem i <- A[l&15][(l>>4)*8 + i]
//   B-frag: lane l, elem i <- B[(l>>4)*8 + i][l&15]
//   C/D   : lane l, reg  r -> C[(l>>4)*4 + r][l&15]
// Split-bf16 GEMM: D += Ah*Bh + Ah*Bl + Al*Bh  (3 MFMAs, fp32 accumulate)
// ============================================================================

// ---------- xs precompute: xs[row] = {hi[128], lo[128]} of split2(ssp(x[row])) ----------
// Removes ~12x redundant per-edge ssp+split VALU (E/N gathers per atom).
__global__ __launch_bounds__(256) void k_xconv(
    const float* __restrict__ x, unsigned short* __restrict__ xs, int total)
{
  int i = (blockIdx.x * 256 + threadIdx.x) * 4;
  if (i >= total) return;
  int row = i >> 7, col = i & 127;
  float4 f4 = *(const float4*)(x + i);
  ushort4 h4, l4;
  split2(ssp(f4.x), h4.x, l4.x);
  split2(ssp(f4.y), h4.y, l4.y);
  split2(ssp(f4.z), h4.z, l4.z);
  split2(ssp(f4.w), h4.w, l4.w);
  *(ushort4*)(xs + (size_t)row * 256 + col)       = h4;
  *(ushort4*)(xs + (size_t)row * 256 + 128 + col) = l4;
}

// ---------- W pre-conversion into split-bf16 B-fragment layout ----------
// ws layout (uint4 = short8 granules of 16B):
//   slot m in [0, nmat): matrix frags, 4096 granules each (64 KB)
//     m=0: Wj | m=1: Wi | m=2..1+ni: Wint[k] | m=2+ni: Wf
//     m=3+ni..2+ni+na: Watm[k] | m=3+ni+na..: Wout[k]
//   slot nmat: Wg frags (1024 granules used)
__global__ __launch_bounds__(256) void k_wconv(
    const float* __restrict__ Wj, const float* __restrict__ Wg,
    const float* __restrict__ Wi, const float* __restrict__ Wf,
    const float* __restrict__ Wint, const float* __restrict__ Watm,
    const float* __restrict__ Wout,
    unsigned short* __restrict__ ws, int ni, int na, int no)
{
  const int nmat = 3 + ni + na + no;
  int t = blockIdx.x * 256 + threadIdx.x;
  int m = t >> 11, r = t & 2047;
  if (m < nmat){
    const float* src;
    if      (m == 0)           src = Wj;
    else if (m == 1)           src = Wi;
    else if (m <= 1 + ni)      src = Wint + (size_t)(m - 2) * 16384;
    else if (m == 2 + ni)      src = Wf;
    else if (m <= 2 + ni + na) src = Watm + (size_t)(m - 3 - ni) * 16384;
    else                       src = Wout + (size_t)(m - 3 - ni - na) * 16384;
    int lane = r & 63, s = (r >> 6) & 3, ct = r >> 8;
    int col = ct * 16 + (lane & 15);
    int k0  = s * 32 + (lane >> 4) * 8;
    union { unsigned short u[8]; uint4 v; } H, L;
#pragma unroll
    for (int i = 0; i < 8; ++i) split2(src[(size_t)(k0 + i) * 128 + col], H.u[i], L.u[i]);
    ((uint4*)ws)[(size_t)m * 4096 + ((ct * 4 + s) * 2 + 0) * 64 + lane] = H.v;
    ((uint4*)ws)[(size_t)m * 4096 + ((ct * 4 + s) * 2 + 1) * 64 + lane] = L.v;
  } else {
    int uu = t - nmat * 2048;
    if (uu < 512){
      int lane = uu & 63, ct = uu >> 6;
      int col = ct * 16 + (lane & 15);
      int k0  = (lane >> 4) * 8;
      union { unsigned short u8[8]; uint4 v; } H, L;
#pragma unroll
      for (int i = 0; i < 8; ++i) split2(Wg[(size_t)(k0 + i) * 128 + col], H.u8[i], L.u8[i]);
      ((uint4*)ws)[(size_t)nmat * 4096 + (ct * 2 + 0) * 64 + lane] = H.v;
      ((uint4*)ws)[(size_t)nmat * 4096 + (ct * 2 + 1) * 64 + lane] = L.v;
    }
  }
}

// ---------- edge kernel: vacc[idx_i] += ssp(ssp(x)[idx_j]@Wj + bj) * (g@Wg) ----------
// A-frags now gathered pre-split from xs (pure loads, no per-edge ssp/split).
__global__ __launch_bounds__(256) void k_edge(
    const unsigned short* __restrict__ xs, const float* __restrict__ g,
    const int* __restrict__ idx_i, const int* __restrict__ idx_j,
    const short8* __restrict__ wjf, const short8* __restrict__ wgf,
    const float* __restrict__ bj, float* vacc, int E)
{
  __shared__ short8 ahl[1024];   // 16 KB: message A, 32 rows x 128 k, hi+lo
  __shared__ short8 ghl[256];    //  4 KB: gate A,    32 rows x  32 k, hi+lo
  __shared__ int    ii_s[32];

  const int t    = threadIdx.x;
  const int lane = t & 63;
  const int w    = t >> 6;
  const int l15  = lane & 15;
  const int lq   = lane >> 4;
  const int e0   = blockIdx.x * 32;

  // --- stage A: gather pre-split rows; thread t -> row t>>3, k-seg (t&7)*16 ---
  {
    const int row = t >> 3, kseg = t & 7;
    int e = e0 + row; if (e >= E) e = E - 1;
    const int j = idx_j[e];
    const short8* xp = (const short8*)(xs + (size_t)j * 256);
    const int q0 = kseg * 2;
    short8 fh0 = xp[q0    ];
    short8 fh1 = xp[q0 + 1];
    short8 fl0 = xp[16 + q0    ];
    short8 fl1 = xp[16 + q0 + 1];
    ahl[0*512 + (q0+0)*32 + (row ^ (q0+0))] = fh0;
    ahl[0*512 + (q0+1)*32 + (row ^ (q0+1))] = fh1;
    ahl[1*512 + (q0+0)*32 + (row ^ (q0+0))] = fl0;
    ahl[1*512 + (q0+1)*32 + (row ^ (q0+1))] = fl1;
  }
  if (t < 64){
    const int row = t >> 1, kseg = t & 1;
    int e = e0 + row; if (e >= E) e = E - 1;
    const float4* gp = (const float4*)(g + (size_t)e * 32 + kseg * 16);
    short8 fh0, fh1, fl0, fl1;
#pragma unroll
    for (int q = 0; q < 4; ++q){
      float4 f4 = gp[q];
      float vv[4] = {f4.x, f4.y, f4.z, f4.w};
#pragma unroll
      for (int uu = 0; uu < 4; ++uu){
        unsigned short hh, ll;
        split2(vv[uu], hh, ll);
        int i = q * 4 + uu;
        if (i < 8){ fh0[i]   = (short)hh; fl0[i]   = (short)ll; }
        else      { fh1[i-8] = (short)hh; fl1[i-8] = (short)ll; }
      }
    }
    const int q0 = kseg * 2;
    ghl[0*128 + (q0+0)*32 + (row ^ (q0+0))] = fh0;
    ghl[0*128 + (q0+1)*32 + (row ^ (q0+1))] = fh1;
    ghl[1*128 + (q0+0)*32 + (row ^ (q0+0))] = fl0;
    ghl[1*128 + (q0+1)*32 + (row ^ (q0+1))] = fl1;
  }
  if (t >= 64 && t < 96){
    int rr = t - 64; int e = e0 + rr;
    ii_s[rr] = (e < E) ? idx_i[e] : -1;
  }
  __syncthreads();

  f32x4 am[2][2], ag[2][2];
#pragma unroll
  for (int a = 0; a < 2; ++a)
#pragma unroll
    for (int b = 0; b < 2; ++b){
      am[a][b] = (f32x4){0.f, 0.f, 0.f, 0.f};
      ag[a][b] = (f32x4){0.f, 0.f, 0.f, 0.f};
    }

#pragma unroll
  for (int s = 0; s < 4; ++s){
    const int q = s * 4 + lq;
    short8 a0h = ahl[0*512 + q*32 + ((l15     ) ^ q)];
    short8 a0l = ahl[1*512 + q*32 + ((l15     ) ^ q)];
    short8 a1h = ahl[0*512 + q*32 + ((16 + l15) ^ q)];
    short8 a1l = ahl[1*512 + q*32 + ((16 + l15) ^ q)];
#pragma unroll
    for (int c = 0; c < 2; ++c){
      const int ct = w * 2 + c;
      short8 bh = wjf[((ct*4 + s)*2 + 0)*64 + lane];
      short8 bl = wjf[((ct*4 + s)*2 + 1)*64 + lane];
      am[0][c] = __builtin_amdgcn_mfma_f32_16x16x32_bf16(a0h, bh, am[0][c], 0, 0, 0);
      am[0][c] = __builtin_amdgcn_mfma_f32_16x16x32_bf16(a0h, bl, am[0][c], 0, 0, 0);
      am[0][c] = __builtin_amdgcn_mfma_f32_16x16x32_bf16(a0l, bh, am[0][c], 0, 0, 0);
      am[1][c] = __builtin_amdgcn_mfma_f32_16x16x32_bf16(a1h, bh, am[1][c], 0, 0, 0);
      am[1][c] = __builtin_amdgcn_mfma_f32_16x16x32_bf16(a1h, bl, am[1][c], 0, 0, 0);
      am[1][c] = __builtin_amdgcn_mfma_f32_16x16x32_bf16(a1l, bh, am[1][c], 0, 0, 0);
    }
  }
  {
    const int q = lq;
    short8 g0h = ghl[0*128 + q*32 + ((l15     ) ^ q)];
    short8 g0l = ghl[1*128 + q*32 + ((l15     ) ^ q)];
    short8 g1h = ghl[0*128 + q*32 + ((16 + l15) ^ q)];
    short8 g1l = ghl[1*128 + q*32 + ((16 + l15) ^ q)];
#pragma unroll
    for (int c = 0; c < 2; ++c){
      const int ct = w * 2 + c;
      short8 bh = wgf[(ct*2 + 0)*64 + lane];
      short8 bl = wgf[(ct*2 + 1)*64 + lane];
      ag[0][c] = __builtin_amdgcn_mfma_f32_16x16x32_bf16(g0h, bh, ag[0][c], 0, 0, 0);
      ag[0][c] = __builtin_amdgcn_mfma_f32_16x16x32_bf16(g0h, bl, ag[0][c], 0, 0, 0);
      ag[0][c] = __builtin_amdgcn_mfma_f32_16x16x32_bf16(g0l, bh, ag[0][c], 0, 0, 0);
      ag[1][c] = __builtin_amdgcn_mfma_f32_16x16x32_bf16(g1h, bh, ag[1][c], 0, 0, 0);
      ag[1][c] = __builtin_amdgcn_mfma_f32_16x16x32_bf16(g1h, bl, ag[1][c], 0, 0, 0);
      ag[1][c] = __builtin_amdgcn_mfma_f32_16x16x32_bf16(g1l, bh, ag[1][c], 0, 0, 0);
    }
  }

#pragma unroll
  for (int c = 0; c < 2; ++c){
    const int col = (w * 2 + c) * 16 + l15;
    const float bjv = bj[col];
#pragma unroll
    for (int rt = 0; rt < 2; ++rt){
#pragma unroll
      for (int r = 0; r < 4; ++r){
        const int row = rt * 16 + lq * 4 + r;
        const int ii  = ii_s[row];
        if (ii >= 0){
          float vp = ssp(am[rt][c][r] + bjv) * ag[rt][c][r];
          atomicAdd(&vacc[(size_t)ii * 128 + col], vp);
        }
      }
    }
  }
}

// ---------- fused atom-side chain, MFMA version (unchanged from round 3) ----------
// 32 rows/block, 256 threads = 4 waves; wave w owns cols [32w, 32w+32).
// NOTE: vacc aliases out[0 : N*128]; each block reads only its own vacc rows
// (layer 0) and writes o to those rows only at kernel end. xs may alias the
// h-half of out: k_edge (sole xs consumer) completes before k_chain launches,
// and within k_chain each block only writes h rows it owns.
__global__ __launch_bounds__(256) void k_chain(
    const float* __restrict__ x, const float* vacc,
    const short8* __restrict__ wcf,   // chain weight frags: slot*4096 granules
    const float* __restrict__ bi, const float* __restrict__ bf_,
    const float* __restrict__ u,
    const float* __restrict__ bint, const float* __restrict__ batm,
    const float* __restrict__ bout,
    float* out, int N, int ni, int na, int no)
{
  __shared__ __align__(16) float arow[32][132];  // padded: +4 breaks bank collisions
  __shared__ short8 ahl[1024];

  const int t    = threadIdx.x;
  const int lane = t & 63;
  const int w    = t >> 6;
  const int l15  = lane & 15;
  const int lq   = lane >> 4;
  const int r0   = blockIdx.x * 32;
  const int srow = t >> 3, skseg = t & 7;   // staging coords: row, 16-elem k-seg

  const int col0 = (w*2 + 0)*16 + l15;
  const int col1 = (w*2 + 1)*16 + l15;

  f32x4 am[2][2];

  auto stage = [&](){
    const float* p = &arow[srow][skseg*16];
    short8 fh0, fh1, fl0, fl1;
#pragma unroll
    for (int i = 0; i < 8; ++i){
      unsigned short hh, ll;
      split2(p[i], hh, ll);
      fh0[i] = (short)hh; fl0[i] = (short)ll;
    }
#pragma unroll
    for (int i = 0; i < 8; ++i){
      unsigned short hh, ll;
      split2(p[8+i], hh, ll);
      fh1[i] = (short)hh; fl1[i] = (short)ll;
    }
    const int q0 = skseg * 2;
    ahl[0*512 + (q0+0)*32 + (srow ^ (q0+0))] = fh0;
    ahl[0*512 + (q0+1)*32 + (srow ^ (q0+1))] = fh1;
    ahl[1*512 + (q0+0)*32 + (srow ^ (q0+0))] = fl0;
    ahl[1*512 + (q0+1)*32 + (srow ^ (q0+1))] = fl1;
  };

  auto gemm = [&](const short8* __restrict__ wf){
#pragma unroll
    for (int a = 0; a < 2; ++a)
#pragma unroll
      for (int b = 0; b < 2; ++b) am[a][b] = (f32x4){0.f, 0.f, 0.f, 0.f};
#pragma unroll
    for (int s = 0; s < 4; ++s){
      const int q = s * 4 + lq;
      short8 a0h = ahl[0*512 + q*32 + ((l15     ) ^ q)];
      short8 a0l = ahl[1*512 + q*32 + ((l15     ) ^ q)];
      short8 a1h = ahl[0*512 + q*32 + ((16 + l15) ^ q)];
      short8 a1l = ahl[1*512 + q*32 + ((16 + l15) ^ q)];
#pragma unroll
      for (int c = 0; c < 2; ++c){
        const int ct = w * 2 + c;
        short8 bh = wf[((ct*4 + s)*2 + 0)*64 + lane];
        short8 bl = wf[((ct*4 + s)*2 + 1)*64 + lane];
        am[0][c] = __builtin_amdgcn_mfma_f32_16x16x32_bf16(a0h, bh, am[0][c], 0, 0, 0);
        am[0][c] = __builtin_amdgcn_mfma_f32_16x16x32_bf16(a0h, bl, am[0][c], 0, 0, 0);
        am[0][c] = __builtin_amdgcn_mfma_f32_16x16x32_bf16(a0l, bh, am[0][c], 0, 0, 0);
        am[1][c] = __builtin_amdgcn_mfma_f32_16x16x32_bf16(a1h, bh, am[1][c], 0, 0, 0);
        am[1][c] = __builtin_amdgcn_mfma_f32_16x16x32_bf16(a1h, bl, am[1][c], 0, 0, 0);
        am[1][c] = __builtin_amdgcn_mfma_f32_16x16x32_bf16(a1l, bh, am[1][c], 0, 0, 0);
      }
    }
  };

  auto put_ssp = [&](float (&st)[2][2][4]){
#pragma unroll
    for (int rt = 0; rt < 2; ++rt)
#pragma unroll
      for (int r = 0; r < 4; ++r){
        const int row = rt*16 + lq*4 + r;
        arow[row][col0] = ssp(st[rt][0][r]);
        arow[row][col1] = ssp(st[rt][1][r]);
      }
  };

  auto residual = [&](float (&st)[2][2][4], const short8* wf, const float* bvec){
    const float b0 = bvec[col0], b1 = bvec[col1];
    put_ssp(st);
    __syncthreads();
    stage();
    __syncthreads();
    gemm(wf);
#pragma unroll
    for (int rt = 0; rt < 2; ++rt)
#pragma unroll
      for (int r = 0; r < 4; ++r){
        const int row = rt*16 + lq*4 + r;
        arow[row][col0] = ssp(am[rt][0][r] + b0);
        arow[row][col1] = ssp(am[rt][1][r] + b1);
      }
    __syncthreads();
    stage();
    __syncthreads();
    gemm(wf);
#pragma unroll
    for (int rt = 0; rt < 2; ++rt)
#pragma unroll
      for (int r = 0; r < 4; ++r){
        st[rt][0][r] += am[rt][0][r] + b0;
        st[rt][1][r] += am[rt][1][r] + b1;
      }
  };

  {
    int row = r0 + srow; if (row >= N) row = N - 1;
    const float4* xp = (const float4*)(x + (size_t)row*128 + skseg*16);
    float* p = &arow[srow][skseg*16];
#pragma unroll
    for (int qq = 0; qq < 4; ++qq){
      float4 f4 = xp[qq];
      p[qq*4+0] = ssp(f4.x); p[qq*4+1] = ssp(f4.y);
      p[qq*4+2] = ssp(f4.z); p[qq*4+3] = ssp(f4.w);
    }
    stage();
  }
  __syncthreads();

  float xar[2][2][4];
#pragma unroll
  for (int rt = 0; rt < 2; ++rt)
#pragma unroll
    for (int r = 0; r < 4; ++r){
      const int row = rt*16 + lq*4 + r;
      xar[rt][0][r] = arow[row][col0];
      xar[rt][1][r] = arow[row][col1];
    }

  gemm(wcf + 0);
  float vst[2][2][4];
  {
    const float b0 = bi[col0], b1 = bi[col1];
#pragma unroll
    for (int rt = 0; rt < 2; ++rt)
#pragma unroll
      for (int r = 0; r < 4; ++r){
        int row = r0 + rt*16 + lq*4 + r; if (row >= N) row = N - 1;
        vst[rt][0][r] = vacc[(size_t)row*128 + col0] + ssp(am[rt][0][r] + b0);
        vst[rt][1][r] = vacc[(size_t)row*128 + col1] + ssp(am[rt][1][r] + b1);
      }
  }

  for (int kk = 0; kk < ni; ++kk)
    residual(vst, wcf + (size_t)(1 + kk) * 4096, bint + kk*128);

  put_ssp(vst);
  __syncthreads();
  stage();
  __syncthreads();
  gemm(wcf + (size_t)(1 + ni) * 4096);
  float hst[2][2][4];
  {
    const float b0 = bf_[col0], b1 = bf_[col1];
    const float u0 = u[col0],   u1 = u[col1];
#pragma unroll
    for (int rt = 0; rt < 2; ++rt)
#pragma unroll
      for (int r = 0; r < 4; ++r){
        hst[rt][0][r] = u0 * xar[rt][0][r] + am[rt][0][r] + b0;
        hst[rt][1][r] = u1 * xar[rt][1][r] + am[rt][1][r] + b1;
      }
  }

  for (int kk = 0; kk < na; ++kk)
    residual(hst, wcf + (size_t)(2 + ni + kk) * 4096, batm + kk*128);

#pragma unroll
  for (int rt = 0; rt < 2; ++rt)
#pragma unroll
    for (int r = 0; r < 4; ++r){
      const int row = r0 + rt*16 + lq*4 + r;
      if (row < N){
        out[(size_t)N*128 + (size_t)row*128 + col0] = hst[rt][0][r];
        out[(size_t)N*128 + (size_t)row*128 + col1] = hst[rt][1][r];
      }
    }

  for (int kk = 0; kk < no; ++kk)
    residual(hst, wcf + (size_t)(2 + ni + na + kk) * 4096, bout + kk*128);

#pragma unroll
  for (int rt = 0; rt < 2; ++rt)
#pragma unroll
    for (int r = 0; r < 4; ++r){
      const int row = r0 + rt*16 + lq*4 + r;
      if (row < N){
        out[(size_t)row*128 + col0] = ssp(hst[rt][0][r]);
        out[(size_t)row*128 + col1] = ssp(hst[rt][1][r]);
      }
    }
}

// ---------- launch ----------
extern "C" void kernel_launch(void* const* d_in, const int* in_sizes, int n_in,
                              void* d_out, int out_size, void* d_ws, size_t ws_size,
                              hipStream_t stream)
{
  const float* x    = (const float*)d_in[0];
  const float* g    = (const float*)d_in[1];
  const float* Wf   = (const float*)d_in[2];
  const float* bf_  = (const float*)d_in[3];
  const float* Wg   = (const float*)d_in[4];
  const float* Wj   = (const float*)d_in[5];
  const float* bj   = (const float*)d_in[6];
  const float* Wi   = (const float*)d_in[7];
  const float* bi   = (const float*)d_in[8];
  const float* u    = (const float*)d_in[9];
  const float* Wint = (const float*)d_in[10];
  const float* bint = (const float*)d_in[11];
  const float* Watm = (const float*)d_in[12];
  const float* batm = (const float*)d_in[13];
  const float* Wout = (const float*)d_in[14];
  const float* bout = (const float*)d_in[15];
  const int* idx_i  = (const int*)d_in[16];
  const int* idx_j  = (const int*)d_in[17];

  const int N  = in_sizes[0] / 128;
  const int E  = in_sizes[16];
  const int ni = in_sizes[10] / 16384;
  const int na = in_sizes[12] / 16384;
  const int no = in_sizes[14] / 16384;

  const int nmat = 3 + ni + na + no;   // Wj, Wi, Wint[ni], Wf, Watm[na], Wout[no]

  // vacc aliases the o-half of d_out (consumed before o is written).
  float* vacc = (float*)d_out;
  short8* wsf = (short8*)d_ws;
  const short8* wjf = wsf;                               // slot 0
  const short8* wcf = wsf + (size_t)1 * 4096;            // slots 1..nmat-1 (chain)
  const short8* wgf = wsf + (size_t)nmat * 4096;         // slot nmat (Wg)

  // xs: pre-split ssp(x), N rows x 512 B. Prefer workspace; else alias the
  // h-half of d_out (safe: k_edge finishes before k_chain; k_chain blocks only
  // write h rows they own, after their own reads).
  const size_t frag_bytes = (size_t)(nmat + 1) * 65536;
  const size_t xs_bytes   = (size_t)N * 256 * sizeof(unsigned short);
  unsigned short* xs;
  if (ws_size >= frag_bytes + xs_bytes)
    xs = (unsigned short*)((char*)d_ws + frag_bytes);
  else
    xs = (unsigned short*)((float*)d_out + (size_t)N * 128);

  hipMemsetAsync(vacc, 0, (size_t)N * 128 * sizeof(float), stream);
  k_xconv<<<dim3((N*128/4 + 255)/256), dim3(256), 0, stream>>>(x, xs, N * 128);
  k_wconv<<<dim3((nmat + 1) * 8), dim3(256), 0, stream>>>(Wj, Wg, Wi, Wf, Wint, Watm, Wout,
                                                          (unsigned short*)d_ws, ni, na, no);
  k_edge <<<dim3((E + 31)/32), dim3(256), 0, stream>>>(xs, g, idx_i, idx_j,
                                                       wjf, wgf, bj, vacc, E);
  k_chain<<<dim3((N + 31)/32), dim3(256), 0, stream>>>(x, vacc, wcf,
                                                       bi, bf_, u, bint, batm, bout,
                                                       (float*)d_out, N, ni, na, no);
}

// Round 5
// 535.720 us; speedup vs baseline: 1.1004x; 1.1004x over previous
//
#include <hip/hip_runtime.h>
#include <stdint.h>

#define LOG2F 0.693147180559945f

typedef __attribute__((ext_vector_type(8))) short short8;
typedef __attribute__((ext_vector_type(4))) float f32x4;

// shifted softplus: softplus(x) - log(2), stable form
__device__ __forceinline__ float ssp(float x){
  float t = __expf(-fabsf(x));
  return fmaxf(x, 0.0f) + __logf(1.0f + t) - LOG2F;
}

// fp32 -> bf16 round-to-nearest-even (16-bit pattern in low bits)
__device__ __forceinline__ uint32_t bf16rn(float x){
  uint32_t u = __float_as_uint(x);
  return (u + 0x7fffu + ((u >> 16) & 1u)) >> 16;
}
// split x ~= hi + lo (both bf16). hi RNE, lo = RNE(x - hi): ~16 mantissa bits kept.
__device__ __forceinline__ void split2(float x, unsigned short &h, unsigned short &l){
  uint32_t hb = bf16rn(x);
  h = (unsigned short)hb;
  float hf = __uint_as_float(hb << 16);
  l = (unsigned short)bf16rn(x - hf);
}

// ============================================================================
// MFMA fragment packing (mfma_f32_16x16x32_bf16) — HW-validated in round 2:
//   A-frag: lane l, elem i <- A[l&15][(l>>4)*8 + i]
//   B-frag: lane l, elem i <- B[(l>>4)*8 + i][l&15]
//   C/D   : lane l, reg  r -> C[(l>>4)*4 + r][l&15]
// Split-bf16 GEMM: D += Ah*Bh + Ah*Bl + Al*Bh  (3 MFMAs, fp32 accumulate)
// ============================================================================

// ---------- xs precompute: xs[row] = {hi[128], lo[128]} of split2(ssp(x[row])) ----------
__global__ __launch_bounds__(256) void k_xconv(
    const float* __restrict__ x, unsigned short* __restrict__ xs, int total)
{
  int i = (blockIdx.x * 256 + threadIdx.x) * 4;
  if (i >= total) return;
  int row = i >> 7, col = i & 127;
  float4 f4 = *(const float4*)(x + i);
  ushort4 h4, l4;
  split2(ssp(f4.x), h4.x, l4.x);
  split2(ssp(f4.y), h4.y, l4.y);
  split2(ssp(f4.z), h4.z, l4.z);
  split2(ssp(f4.w), h4.w, l4.w);
  *(ushort4*)(xs + (size_t)row * 256 + col)       = h4;
  *(ushort4*)(xs + (size_t)row * 256 + 128 + col) = l4;
}

// ---------- counting sort of edges by idx_i (bijective permutation) ----------
__global__ __launch_bounds__(256) void k_hist(
    const int* __restrict__ idx_i, int* __restrict__ cnt, int E)
{
  int e = blockIdx.x * 256 + threadIdx.x;
  if (e < E) atomicAdd(&cnt[idx_i[e]], 1);
}

// exclusive scan, 2048 elems/block; in-place on cnt; block totals to bsums
__global__ __launch_bounds__(256) void k_scan1(
    int* __restrict__ cnt, int* __restrict__ bsums, int N)
{
  __shared__ int sh[256];
  const int t = threadIdx.x;
  const int base = blockIdx.x * 2048 + t * 8;
  int loc[8], s = 0;
#pragma unroll
  for (int k = 0; k < 8; ++k){
    int v = (base + k < N) ? cnt[base + k] : 0;
    loc[k] = s; s += v;
  }
  sh[t] = s;
  __syncthreads();
  const int own = s;
  for (int off = 1; off < 256; off <<= 1){
    int v = (t >= off) ? sh[t - off] : 0;
    __syncthreads();
    sh[t] += v;
    __syncthreads();
  }
  const int ex = sh[t] - own;
#pragma unroll
  for (int k = 0; k < 8; ++k)
    if (base + k < N) cnt[base + k] = ex + loc[k];
  if (t == 255) bsums[blockIdx.x] = sh[255];
}

__global__ void k_scan2(int* __restrict__ bsums, int nblk){
  if (threadIdx.x == 0 && blockIdx.x == 0){
    int run = 0;
    for (int b = 0; b < nblk; ++b){ int v = bsums[b]; bsums[b] = run; run += v; }
  }
}

__global__ __launch_bounds__(256) void k_scan3(
    int* __restrict__ cnt, const int* __restrict__ bsums, int N)
{
  int i = blockIdx.x * 256 + threadIdx.x;
  if (i < N) cnt[i] += bsums[i >> 11];
}

__global__ __launch_bounds__(256) void k_scatter(
    const int* __restrict__ idx_i, int* __restrict__ ofs,
    int* __restrict__ perm, int E)
{
  int e = blockIdx.x * 256 + threadIdx.x;
  if (e < E){
    int p = atomicAdd(&ofs[idx_i[e]], 1);
    perm[p] = e;
  }
}

// ---------- W pre-conversion into split-bf16 B-fragment layout ----------
// ws layout: slot m in [0,nmat): 4096 granules (64 KB) each:
//   m=0: Wj | m=1: Wi | m=2..1+ni: Wint[k] | m=2+ni: Wf
//   m=3+ni..2+ni+na: Watm[k] | m=3+ni+na..: Wout[k]  | slot nmat: Wg
__global__ __launch_bounds__(256) void k_wconv(
    const float* __restrict__ Wj, const float* __restrict__ Wg,
    const float* __restrict__ Wi, const float* __restrict__ Wf,
    const float* __restrict__ Wint, const float* __restrict__ Watm,
    const float* __restrict__ Wout,
    unsigned short* __restrict__ ws, int ni, int na, int no)
{
  const int nmat = 3 + ni + na + no;
  int t = blockIdx.x * 256 + threadIdx.x;
  int m = t >> 11, r = t & 2047;
  if (m < nmat){
    const float* src;
    if      (m == 0)           src = Wj;
    else if (m == 1)           src = Wi;
    else if (m <= 1 + ni)      src = Wint + (size_t)(m - 2) * 16384;
    else if (m == 2 + ni)      src = Wf;
    else if (m <= 2 + ni + na) src = Watm + (size_t)(m - 3 - ni) * 16384;
    else                       src = Wout + (size_t)(m - 3 - ni - na) * 16384;
    int lane = r & 63, s = (r >> 6) & 3, ct = r >> 8;
    int col = ct * 16 + (lane & 15);
    int k0  = s * 32 + (lane >> 4) * 8;
    union { unsigned short u[8]; uint4 v; } H, L;
#pragma unroll
    for (int i = 0; i < 8; ++i) split2(src[(size_t)(k0 + i) * 128 + col], H.u[i], L.u[i]);
    ((uint4*)ws)[(size_t)m * 4096 + ((ct * 4 + s) * 2 + 0) * 64 + lane] = H.v;
    ((uint4*)ws)[(size_t)m * 4096 + ((ct * 4 + s) * 2 + 1) * 64 + lane] = L.v;
  } else {
    int uu = t - nmat * 2048;
    if (uu < 512){
      int lane = uu & 63, ct = uu >> 6;
      int col = ct * 16 + (lane & 15);
      int k0  = (lane >> 4) * 8;
      union { unsigned short u8[8]; uint4 v; } H, L;
#pragma unroll
      for (int i = 0; i < 8; ++i) split2(Wg[(size_t)(k0 + i) * 128 + col], H.u8[i], L.u8[i]);
      ((uint4*)ws)[(size_t)nmat * 4096 + (ct * 2 + 0) * 64 + lane] = H.v;
      ((uint4*)ws)[(size_t)nmat * 4096 + (ct * 2 + 1) * 64 + lane] = L.v;
    }
  }
}

// ---------- edge kernel (CSR-ordered): segmented per-tile reduce, few atomics ----------
// Edges processed in perm order (sorted by idx_i). After MFMA, vp rows go to LDS;
// a 32-row serial segmented scan flushes ONE atomicAdd per distinct atom per tile.
__global__ __launch_bounds__(256) void k_edge(
    const unsigned short* __restrict__ xs, const float* __restrict__ g,
    const int* __restrict__ idx_i, const int* __restrict__ idx_j,
    const int* __restrict__ perm,
    const short8* __restrict__ wjf, const short8* __restrict__ wgf,
    const float* __restrict__ bj, float* vacc, int E)
{
  // ahl 16 KB + ghl 4 KB; vp_s (32x132 f32 = 16.5 KB) reuses the same buffer
  __shared__ __align__(16) char smem[16384 + 4096];
  short8* ahl = (short8*)smem;
  short8* ghl = (short8*)(smem + 16384);
  float*  vp_s = (float*)smem;
  __shared__ int ii_s[32];

  const int t    = threadIdx.x;
  const int lane = t & 63;
  const int w    = t >> 6;
  const int l15  = lane & 15;
  const int lq   = lane >> 4;
  const int e0   = blockIdx.x * 32;

  // --- stage A: gather pre-split rows of permuted edges ---
  {
    const int row = t >> 3, kseg = t & 7;
    const int pe = e0 + row;
    const int e = (pe < E) ? perm[pe] : 0;
    const int j = idx_j[e];
    const short8* xp = (const short8*)(xs + (size_t)j * 256);
    const int q0 = kseg * 2;
    short8 fh0 = xp[q0    ];
    short8 fh1 = xp[q0 + 1];
    short8 fl0 = xp[16 + q0    ];
    short8 fl1 = xp[16 + q0 + 1];
    ahl[0*512 + (q0+0)*32 + (row ^ (q0+0))] = fh0;
    ahl[0*512 + (q0+1)*32 + (row ^ (q0+1))] = fh1;
    ahl[1*512 + (q0+0)*32 + (row ^ (q0+0))] = fl0;
    ahl[1*512 + (q0+1)*32 + (row ^ (q0+1))] = fl1;
  }
  if (t < 64){
    const int row = t >> 1, kseg = t & 1;
    const int pe = e0 + row;
    const int e = (pe < E) ? perm[pe] : 0;
    const float4* gp = (const float4*)(g + (size_t)e * 32 + kseg * 16);
    short8 fh0, fh1, fl0, fl1;
#pragma unroll
    for (int q = 0; q < 4; ++q){
      float4 f4 = gp[q];
      float vv[4] = {f4.x, f4.y, f4.z, f4.w};
#pragma unroll
      for (int uu = 0; uu < 4; ++uu){
        unsigned short hh, ll;
        split2(vv[uu], hh, ll);
        int i = q * 4 + uu;
        if (i < 8){ fh0[i]   = (short)hh; fl0[i]   = (short)ll; }
        else      { fh1[i-8] = (short)hh; fl1[i-8] = (short)ll; }
      }
    }
    const int q0 = kseg * 2;
    ghl[0*128 + (q0+0)*32 + (row ^ (q0+0))] = fh0;
    ghl[0*128 + (q0+1)*32 + (row ^ (q0+1))] = fh1;
    ghl[1*128 + (q0+0)*32 + (row ^ (q0+0))] = fl0;
    ghl[1*128 + (q0+1)*32 + (row ^ (q0+1))] = fl1;
  }
  if (t >= 64 && t < 96){
    int rr = t - 64, pe = e0 + rr;
    ii_s[rr] = (pe < E) ? idx_i[perm[pe]] : -1;
  }
  __syncthreads();

  f32x4 am[2][2], ag[2][2];
#pragma unroll
  for (int a = 0; a < 2; ++a)
#pragma unroll
    for (int b = 0; b < 2; ++b){
      am[a][b] = (f32x4){0.f, 0.f, 0.f, 0.f};
      ag[a][b] = (f32x4){0.f, 0.f, 0.f, 0.f};
    }

#pragma unroll
  for (int s = 0; s < 4; ++s){
    const int q = s * 4 + lq;
    short8 a0h = ahl[0*512 + q*32 + ((l15     ) ^ q)];
    short8 a0l = ahl[1*512 + q*32 + ((l15     ) ^ q)];
    short8 a1h = ahl[0*512 + q*32 + ((16 + l15) ^ q)];
    short8 a1l = ahl[1*512 + q*32 + ((16 + l15) ^ q)];
#pragma unroll
    for (int c = 0; c < 2; ++c){
      const int ct = w * 2 + c;
      short8 bh = wjf[((ct*4 + s)*2 + 0)*64 + lane];
      short8 bl = wjf[((ct*4 + s)*2 + 1)*64 + lane];
      am[0][c] = __builtin_amdgcn_mfma_f32_16x16x32_bf16(a0h, bh, am[0][c], 0, 0, 0);
      am[0][c] = __builtin_amdgcn_mfma_f32_16x16x32_bf16(a0h, bl, am[0][c], 0, 0, 0);
      am[0][c] = __builtin_amdgcn_mfma_f32_16x16x32_bf16(a0l, bh, am[0][c], 0, 0, 0);
      am[1][c] = __builtin_amdgcn_mfma_f32_16x16x32_bf16(a1h, bh, am[1][c], 0, 0, 0);
      am[1][c] = __builtin_amdgcn_mfma_f32_16x16x32_bf16(a1h, bl, am[1][c], 0, 0, 0);
      am[1][c] = __builtin_amdgcn_mfma_f32_16x16x32_bf16(a1l, bh, am[1][c], 0, 0, 0);
    }
  }
  {
    const int q = lq;
    short8 g0h = ghl[0*128 + q*32 + ((l15     ) ^ q)];
    short8 g0l = ghl[1*128 + q*32 + ((l15     ) ^ q)];
    short8 g1h = ghl[0*128 + q*32 + ((16 + l15) ^ q)];
    short8 g1l = ghl[1*128 + q*32 + ((16 + l15) ^ q)];
#pragma unroll
    for (int c = 0; c < 2; ++c){
      const int ct = w * 2 + c;
      short8 bh = wgf[(ct*2 + 0)*64 + lane];
      short8 bl = wgf[(ct*2 + 1)*64 + lane];
      ag[0][c] = __builtin_amdgcn_mfma_f32_16x16x32_bf16(g0h, bh, ag[0][c], 0, 0, 0);
      ag[0][c] = __builtin_amdgcn_mfma_f32_16x16x32_bf16(g0h, bl, ag[0][c], 0, 0, 0);
      ag[0][c] = __builtin_amdgcn_mfma_f32_16x16x32_bf16(g0l, bh, ag[0][c], 0, 0, 0);
      ag[1][c] = __builtin_amdgcn_mfma_f32_16x16x32_bf16(g1h, bh, ag[1][c], 0, 0, 0);
      ag[1][c] = __builtin_amdgcn_mfma_f32_16x16x32_bf16(g1h, bl, ag[1][c], 0, 0, 0);
      ag[1][c] = __builtin_amdgcn_mfma_f32_16x16x32_bf16(g1l, bh, ag[1][c], 0, 0, 0);
    }
  }

  // --- epilogue: vp -> LDS, then segmented scan + per-segment atomic flush ---
  __syncthreads();   // all MFMA operand reads from ahl/ghl are done
#pragma unroll
  for (int c = 0; c < 2; ++c){
    const int col = (w * 2 + c) * 16 + l15;
    const float bjv = bj[col];
#pragma unroll
    for (int rt = 0; rt < 2; ++rt)
#pragma unroll
      for (int r = 0; r < 4; ++r){
        const int row = rt * 16 + lq * 4 + r;
        vp_s[row * 132 + col] = ssp(am[rt][c][r] + bjv) * ag[rt][c][r];
      }
  }
  __syncthreads();
  if (t < 128){
    const int col = t;
    float acc = vp_s[col];
    int cur = ii_s[0];
    for (int r = 1; r < 32; ++r){
      const int ii = ii_s[r];
      const float v = vp_s[r * 132 + col];
      if (ii == cur) acc += v;
      else {
        if (cur >= 0) atomicAdd(&vacc[(size_t)cur * 128 + col], acc);
        acc = v; cur = ii;
      }
    }
    if (cur >= 0) atomicAdd(&vacc[(size_t)cur * 128 + col], acc);
  }
}

// ---------- fused atom-side chain, MFMA version (frozen from round 3) ----------
// NOTE: vacc aliases out[0 : N*128]; xs may alias the h-half (k_edge completes
// before k_chain; each k_chain block only writes rows it owns, after its reads).
__global__ __launch_bounds__(256) void k_chain(
    const float* __restrict__ x, const float* vacc,
    const short8* __restrict__ wcf,
    const float* __restrict__ bi, const float* __restrict__ bf_,
    const float* __restrict__ u,
    const float* __restrict__ bint, const float* __restrict__ batm,
    const float* __restrict__ bout,
    float* out, int N, int ni, int na, int no)
{
  __shared__ __align__(16) float arow[32][132];
  __shared__ short8 ahl[1024];

  const int t    = threadIdx.x;
  const int lane = t & 63;
  const int w    = t >> 6;
  const int l15  = lane & 15;
  const int lq   = lane >> 4;
  const int r0   = blockIdx.x * 32;
  const int srow = t >> 3, skseg = t & 7;

  const int col0 = (w*2 + 0)*16 + l15;
  const int col1 = (w*2 + 1)*16 + l15;

  f32x4 am[2][2];

  auto stage = [&](){
    const float* p = &arow[srow][skseg*16];
    short8 fh0, fh1, fl0, fl1;
#pragma unroll
    for (int i = 0; i < 8; ++i){
      unsigned short hh, ll;
      split2(p[i], hh, ll);
      fh0[i] = (short)hh; fl0[i] = (short)ll;
    }
#pragma unroll
    for (int i = 0; i < 8; ++i){
      unsigned short hh, ll;
      split2(p[8+i], hh, ll);
      fh1[i] = (short)hh; fl1[i] = (short)ll;
    }
    const int q0 = skseg * 2;
    ahl[0*512 + (q0+0)*32 + (srow ^ (q0+0))] = fh0;
    ahl[0*512 + (q0+1)*32 + (srow ^ (q0+1))] = fh1;
    ahl[1*512 + (q0+0)*32 + (srow ^ (q0+0))] = fl0;
    ahl[1*512 + (q0+1)*32 + (srow ^ (q0+1))] = fl1;
  };

  auto gemm = [&](const short8* __restrict__ wf){
#pragma unroll
    for (int a = 0; a < 2; ++a)
#pragma unroll
      for (int b = 0; b < 2; ++b) am[a][b] = (f32x4){0.f, 0.f, 0.f, 0.f};
#pragma unroll
    for (int s = 0; s < 4; ++s){
      const int q = s * 4 + lq;
      short8 a0h = ahl[0*512 + q*32 + ((l15     ) ^ q)];
      short8 a0l = ahl[1*512 + q*32 + ((l15     ) ^ q)];
      short8 a1h = ahl[0*512 + q*32 + ((16 + l15) ^ q)];
      short8 a1l = ahl[1*512 + q*32 + ((16 + l15) ^ q)];
#pragma unroll
      for (int c = 0; c < 2; ++c){
        const int ct = w * 2 + c;
        short8 bh = wf[((ct*4 + s)*2 + 0)*64 + lane];
        short8 bl = wf[((ct*4 + s)*2 + 1)*64 + lane];
        am[0][c] = __builtin_amdgcn_mfma_f32_16x16x32_bf16(a0h, bh, am[0][c], 0, 0, 0);
        am[0][c] = __builtin_amdgcn_mfma_f32_16x16x32_bf16(a0h, bl, am[0][c], 0, 0, 0);
        am[0][c] = __builtin_amdgcn_mfma_f32_16x16x32_bf16(a0l, bh, am[0][c], 0, 0, 0);
        am[1][c] = __builtin_amdgcn_mfma_f32_16x16x32_bf16(a1h, bh, am[1][c], 0, 0, 0);
        am[1][c] = __builtin_amdgcn_mfma_f32_16x16x32_bf16(a1h, bl, am[1][c], 0, 0, 0);
        am[1][c] = __builtin_amdgcn_mfma_f32_16x16x32_bf16(a1l, bh, am[1][c], 0, 0, 0);
      }
    }
  };

  auto put_ssp = [&](float (&st)[2][2][4]){
#pragma unroll
    for (int rt = 0; rt < 2; ++rt)
#pragma unroll
      for (int r = 0; r < 4; ++r){
        const int row = rt*16 + lq*4 + r;
        arow[row][col0] = ssp(st[rt][0][r]);
        arow[row][col1] = ssp(st[rt][1][r]);
      }
  };

  auto residual = [&](float (&st)[2][2][4], const short8* wf, const float* bvec){
    const float b0 = bvec[col0], b1 = bvec[col1];
    put_ssp(st);
    __syncthreads();
    stage();
    __syncthreads();
    gemm(wf);
#pragma unroll
    for (int rt = 0; rt < 2; ++rt)
#pragma unroll
      for (int r = 0; r < 4; ++r){
        const int row = rt*16 + lq*4 + r;
        arow[row][col0] = ssp(am[rt][0][r] + b0);
        arow[row][col1] = ssp(am[rt][1][r] + b1);
      }
    __syncthreads();
    stage();
    __syncthreads();
    gemm(wf);
#pragma unroll
    for (int rt = 0; rt < 2; ++rt)
#pragma unroll
      for (int r = 0; r < 4; ++r){
        st[rt][0][r] += am[rt][0][r] + b0;
        st[rt][1][r] += am[rt][1][r] + b1;
      }
  };

  {
    int row = r0 + srow; if (row >= N) row = N - 1;
    const float4* xp = (const float4*)(x + (size_t)row*128 + skseg*16);
    float* p = &arow[srow][skseg*16];
#pragma unroll
    for (int qq = 0; qq < 4; ++qq){
      float4 f4 = xp[qq];
      p[qq*4+0] = ssp(f4.x); p[qq*4+1] = ssp(f4.y);
      p[qq*4+2] = ssp(f4.z); p[qq*4+3] = ssp(f4.w);
    }
    stage();
  }
  __syncthreads();

  float xar[2][2][4];
#pragma unroll
  for (int rt = 0; rt < 2; ++rt)
#pragma unroll
    for (int r = 0; r < 4; ++r){
      const int row = rt*16 + lq*4 + r;
      xar[rt][0][r] = arow[row][col0];
      xar[rt][1][r] = arow[row][col1];
    }

  gemm(wcf + 0);
  float vst[2][2][4];
  {
    const float b0 = bi[col0], b1 = bi[col1];
#pragma unroll
    for (int rt = 0; rt < 2; ++rt)
#pragma unroll
      for (int r = 0; r < 4; ++r){
        int row = r0 + rt*16 + lq*4 + r; if (row >= N) row = N - 1;
        vst[rt][0][r] = vacc[(size_t)row*128 + col0] + ssp(am[rt][0][r] + b0);
        vst[rt][1][r] = vacc[(size_t)row*128 + col1] + ssp(am[rt][1][r] + b1);
      }
  }

  for (int kk = 0; kk < ni; ++kk)
    residual(vst, wcf + (size_t)(1 + kk) * 4096, bint + kk*128);

  put_ssp(vst);
  __syncthreads();
  stage();
  __syncthreads();
  gemm(wcf + (size_t)(1 + ni) * 4096);
  float hst[2][2][4];
  {
    const float b0 = bf_[col0], b1 = bf_[col1];
    const float u0 = u[col0],   u1 = u[col1];
#pragma unroll
    for (int rt = 0; rt < 2; ++rt)
#pragma unroll
      for (int r = 0; r < 4; ++r){
        hst[rt][0][r] = u0 * xar[rt][0][r] + am[rt][0][r] + b0;
        hst[rt][1][r] = u1 * xar[rt][1][r] + am[rt][1][r] + b1;
      }
  }

  for (int kk = 0; kk < na; ++kk)
    residual(hst, wcf + (size_t)(2 + ni + kk) * 4096, batm + kk*128);

#pragma unroll
  for (int rt = 0; rt < 2; ++rt)
#pragma unroll
    for (int r = 0; r < 4; ++r){
      const int row = r0 + rt*16 + lq*4 + r;
      if (row < N){
        out[(size_t)N*128 + (size_t)row*128 + col0] = hst[rt][0][r];
        out[(size_t)N*128 + (size_t)row*128 + col1] = hst[rt][1][r];
      }
    }

  for (int kk = 0; kk < no; ++kk)
    residual(hst, wcf + (size_t)(2 + ni + na + kk) * 4096, bout + kk*128);

#pragma unroll
  for (int rt = 0; rt < 2; ++rt)
#pragma unroll
    for (int r = 0; r < 4; ++r){
      const int row = r0 + rt*16 + lq*4 + r;
      if (row < N){
        out[(size_t)row*128 + col0] = ssp(hst[rt][0][r]);
        out[(size_t)row*128 + col1] = ssp(hst[rt][1][r]);
      }
    }
}

// ---------- launch ----------
extern "C" void kernel_launch(void* const* d_in, const int* in_sizes, int n_in,
                              void* d_out, int out_size, void* d_ws, size_t ws_size,
                              hipStream_t stream)
{
  const float* x    = (const float*)d_in[0];
  const float* g    = (const float*)d_in[1];
  const float* Wf   = (const float*)d_in[2];
  const float* bf_  = (const float*)d_in[3];
  const float* Wg   = (const float*)d_in[4];
  const float* Wj   = (const float*)d_in[5];
  const float* bj   = (const float*)d_in[6];
  const float* Wi   = (const float*)d_in[7];
  const float* bi   = (const float*)d_in[8];
  const float* u    = (const float*)d_in[9];
  const float* Wint = (const float*)d_in[10];
  const float* bint = (const float*)d_in[11];
  const float* Watm = (const float*)d_in[12];
  const float* batm = (const float*)d_in[13];
  const float* Wout = (const float*)d_in[14];
  const float* bout = (const float*)d_in[15];
  const int* idx_i  = (const int*)d_in[16];
  const int* idx_j  = (const int*)d_in[17];

  const int N  = in_sizes[0] / 128;
  const int E  = in_sizes[16];
  const int ni = in_sizes[10] / 16384;
  const int na = in_sizes[12] / 16384;
  const int no = in_sizes[14] / 16384;

  const int nmat = 3 + ni + na + no;

  // vacc aliases the o-half of d_out (consumed before o is written).
  float* vacc = (float*)d_out;
  short8* wsf = (short8*)d_ws;
  const short8* wjf = wsf;                       // slot 0
  const short8* wcf = wsf + (size_t)1 * 4096;    // slots 1..nmat-1 (chain)
  const short8* wgf = wsf + (size_t)nmat * 4096; // slot nmat (Wg)

  // d_ws layout after frags: cnt[N] (doubles as ofs), bsums[1024], perm[E], xs
  const size_t frag_bytes = (size_t)(nmat + 1) * 65536;
  int* cnt   = (int*)((char*)d_ws + frag_bytes);
  int* bsums = cnt + N;
  int* perm  = bsums + 1024;
  char* after = (char*)(perm + E);
  const size_t used = (size_t)(after - (char*)d_ws);
  const size_t xs_bytes = (size_t)N * 256 * sizeof(unsigned short);
  unsigned short* xs = (ws_size >= used + xs_bytes)
      ? (unsigned short*)after
      : (unsigned short*)((float*)d_out + (size_t)N * 128);

  const int nblk = (N + 2047) / 2048;

  hipMemsetAsync(vacc, 0, (size_t)N * 128 * sizeof(float), stream);
  hipMemsetAsync(cnt, 0, (size_t)N * sizeof(int), stream);
  k_xconv  <<<dim3((N*128/4 + 255)/256), dim3(256), 0, stream>>>(x, xs, N * 128);
  k_wconv  <<<dim3((nmat + 1) * 8), dim3(256), 0, stream>>>(Wj, Wg, Wi, Wf, Wint, Watm, Wout,
                                                            (unsigned short*)d_ws, ni, na, no);
  k_hist   <<<dim3((E + 255)/256), dim3(256), 0, stream>>>(idx_i, cnt, E);
  k_scan1  <<<dim3(nblk), dim3(256), 0, stream>>>(cnt, bsums, N);
  k_scan2  <<<dim3(1), dim3(64), 0, stream>>>(bsums, nblk);
  k_scan3  <<<dim3((N + 255)/256), dim3(256), 0, stream>>>(cnt, bsums, N);
  k_scatter<<<dim3((E + 255)/256), dim3(256), 0, stream>>>(idx_i, cnt, perm, E);
  k_edge   <<<dim3((E + 31)/32), dim3(256), 0, stream>>>(xs, g, idx_i, idx_j, perm,
                                                         wjf, wgf, bj, vacc, E);
  k_chain  <<<dim3((N + 31)/32), dim3(256), 0, stream>>>(x, vacc, wcf,
                                                         bi, bf_, u, bint, batm, bout,
                                                         (float*)d_out, N, ni, na, no);
}

// Round 6
// 533.446 us; speedup vs baseline: 1.1051x; 1.0043x over previous
//
#include <hip/hip_runtime.h>
#include <stdint.h>

#define LOG2F 0.693147180559945f

typedef __attribute__((ext_vector_type(8))) short short8;
typedef __attribute__((ext_vector_type(4))) float f32x4;

// shifted softplus: softplus(x) - log(2), stable form
__device__ __forceinline__ float ssp(float x){
  float t = __expf(-fabsf(x));
  return fmaxf(x, 0.0f) + __logf(1.0f + t) - LOG2F;
}

// fp32 -> bf16 round-to-nearest-even (16-bit pattern in low bits)
__device__ __forceinline__ uint32_t bf16rn(float x){
  uint32_t u = __float_as_uint(x);
  return (u + 0x7fffu + ((u >> 16) & 1u)) >> 16;
}
// split x ~= hi + lo (both bf16). hi RNE, lo = RNE(x - hi): ~16 mantissa bits kept.
__device__ __forceinline__ void split2(float x, unsigned short &h, unsigned short &l){
  uint32_t hb = bf16rn(x);
  h = (unsigned short)hb;
  float hf = __uint_as_float(hb << 16);
  l = (unsigned short)bf16rn(x - hf);
}

// ============================================================================
// MFMA fragment packing (mfma_f32_16x16x32_bf16) — HW-validated in round 2:
//   A-frag: lane l, elem i <- A[l&15][(l>>4)*8 + i]
//   B-frag: lane l, elem i <- B[(l>>4)*8 + i][l&15]
//   C/D   : lane l, reg  r -> C[(l>>4)*4 + r][l&15]
// Split-bf16 GEMM: D += Ah*Bh + Ah*Bl + Al*Bh  (3 MFMAs, fp32 accumulate)
// Frag LDS layout: granule g = hl*512 + q*32 + (row^q), elem i = col&7,
//   where q = col>>3  (XOR swizzle keeps stores/loads ~2-way banked).
// ============================================================================

// ---------- xs precompute: xs[row] = {hi[128], lo[128]} of split2(ssp(x[row])) ----------
__global__ __launch_bounds__(256) void k_xconv(
    const float* __restrict__ x, unsigned short* __restrict__ xs, int total)
{
  int i = (blockIdx.x * 256 + threadIdx.x) * 4;
  if (i >= total) return;
  int row = i >> 7, col = i & 127;
  float4 f4 = *(const float4*)(x + i);
  ushort4 h4, l4;
  split2(ssp(f4.x), h4.x, l4.x);
  split2(ssp(f4.y), h4.y, l4.y);
  split2(ssp(f4.z), h4.z, l4.z);
  split2(ssp(f4.w), h4.w, l4.w);
  *(ushort4*)(xs + (size_t)row * 256 + col)       = h4;
  *(ushort4*)(xs + (size_t)row * 256 + 128 + col) = l4;
}

// ---------- counting sort of edges by idx_i (bijective permutation) ----------
__global__ __launch_bounds__(256) void k_hist(
    const int* __restrict__ idx_i, int* __restrict__ cnt, int E)
{
  int e = blockIdx.x * 256 + threadIdx.x;
  if (e < E) atomicAdd(&cnt[idx_i[e]], 1);
}

__global__ __launch_bounds__(256) void k_scan1(
    int* __restrict__ cnt, int* __restrict__ bsums, int N)
{
  __shared__ int sh[256];
  const int t = threadIdx.x;
  const int base = blockIdx.x * 2048 + t * 8;
  int loc[8], s = 0;
#pragma unroll
  for (int k = 0; k < 8; ++k){
    int v = (base + k < N) ? cnt[base + k] : 0;
    loc[k] = s; s += v;
  }
  sh[t] = s;
  __syncthreads();
  const int own = s;
  for (int off = 1; off < 256; off <<= 1){
    int v = (t >= off) ? sh[t - off] : 0;
    __syncthreads();
    sh[t] += v;
    __syncthreads();
  }
  const int ex = sh[t] - own;
#pragma unroll
  for (int k = 0; k < 8; ++k)
    if (base + k < N) cnt[base + k] = ex + loc[k];
  if (t == 255) bsums[blockIdx.x] = sh[255];
}

__global__ void k_scan2(int* __restrict__ bsums, int nblk){
  if (threadIdx.x == 0 && blockIdx.x == 0){
    int run = 0;
    for (int b = 0; b < nblk; ++b){ int v = bsums[b]; bsums[b] = run; run += v; }
  }
}

__global__ __launch_bounds__(256) void k_scan3(
    int* __restrict__ cnt, const int* __restrict__ bsums, int N)
{
  int i = blockIdx.x * 256 + threadIdx.x;
  if (i < N) cnt[i] += bsums[i >> 11];
}

__global__ __launch_bounds__(256) void k_scatter(
    const int* __restrict__ idx_i, int* __restrict__ ofs,
    int* __restrict__ perm, int E)
{
  int e = blockIdx.x * 256 + threadIdx.x;
  if (e < E){
    int p = atomicAdd(&ofs[idx_i[e]], 1);
    perm[p] = e;
  }
}

// ---------- W pre-conversion into split-bf16 B-fragment layout ----------
// ws layout: slot m in [0,nmat): 4096 granules (64 KB) each:
//   m=0: Wj | m=1: Wi | m=2..1+ni: Wint[k] | m=2+ni: Wf
//   m=3+ni..2+ni+na: Watm[k] | m=3+ni+na..: Wout[k]  | slot nmat: Wg
__global__ __launch_bounds__(256) void k_wconv(
    const float* __restrict__ Wj, const float* __restrict__ Wg,
    const float* __restrict__ Wi, const float* __restrict__ Wf,
    const float* __restrict__ Wint, const float* __restrict__ Watm,
    const float* __restrict__ Wout,
    unsigned short* __restrict__ ws, int ni, int na, int no)
{
  const int nmat = 3 + ni + na + no;
  int t = blockIdx.x * 256 + threadIdx.x;
  int m = t >> 11, r = t & 2047;
  if (m < nmat){
    const float* src;
    if      (m == 0)           src = Wj;
    else if (m == 1)           src = Wi;
    else if (m <= 1 + ni)      src = Wint + (size_t)(m - 2) * 16384;
    else if (m == 2 + ni)      src = Wf;
    else if (m <= 2 + ni + na) src = Watm + (size_t)(m - 3 - ni) * 16384;
    else                       src = Wout + (size_t)(m - 3 - ni - na) * 16384;
    int lane = r & 63, s = (r >> 6) & 3, ct = r >> 8;
    int col = ct * 16 + (lane & 15);
    int k0  = s * 32 + (lane >> 4) * 8;
    union { unsigned short u[8]; uint4 v; } H, L;
#pragma unroll
    for (int i = 0; i < 8; ++i) split2(src[(size_t)(k0 + i) * 128 + col], H.u[i], L.u[i]);
    ((uint4*)ws)[(size_t)m * 4096 + ((ct * 4 + s) * 2 + 0) * 64 + lane] = H.v;
    ((uint4*)ws)[(size_t)m * 4096 + ((ct * 4 + s) * 2 + 1) * 64 + lane] = L.v;
  } else {
    int uu = t - nmat * 2048;
    if (uu < 512){
      int lane = uu & 63, ct = uu >> 6;
      int col = ct * 16 + (lane & 15);
      int k0  = (lane >> 4) * 8;
      union { unsigned short u8[8]; uint4 v; } H, L;
#pragma unroll
      for (int i = 0; i < 8; ++i) split2(Wg[(size_t)(k0 + i) * 128 + col], H.u8[i], L.u8[i]);
      ((uint4*)ws)[(size_t)nmat * 4096 + (ct * 2 + 0) * 64 + lane] = H.v;
      ((uint4*)ws)[(size_t)nmat * 4096 + (ct * 2 + 1) * 64 + lane] = L.v;
    }
  }
}

// ---------- edge kernel (CSR-ordered): segmented per-tile reduce, few atomics ----------
// Epilogue v2: vp stored TRANSPOSED [col][33] (bank = (col+row)%32, ~2-way),
// flush parallelized across all 256 threads (col = t&127, 16-row half = t>>7).
// A half-boundary-spanning segment flushes two atomics — additive, correct.
__global__ __launch_bounds__(256) void k_edge(
    const unsigned short* __restrict__ xs, const float* __restrict__ g,
    const int* __restrict__ idx_i, const int* __restrict__ idx_j,
    const int* __restrict__ perm,
    const short8* __restrict__ wjf, const short8* __restrict__ wgf,
    const float* __restrict__ bj, float* vacc, int E)
{
  // ahl 16 KB + ghl 4 KB; vp_s (128 x 33 f32 = 16.9 KB) reuses the same buffer
  __shared__ __align__(16) char smem[16384 + 4096];
  short8* ahl = (short8*)smem;
  short8* ghl = (short8*)(smem + 16384);
  float*  vp_s = (float*)smem;
  __shared__ int ii_s[32];

  const int t    = threadIdx.x;
  const int lane = t & 63;
  const int w    = t >> 6;
  const int l15  = lane & 15;
  const int lq   = lane >> 4;
  const int e0   = blockIdx.x * 32;

  // --- stage A: gather pre-split rows of permuted edges ---
  {
    const int row = t >> 3, kseg = t & 7;
    const int pe = e0 + row;
    const int e = (pe < E) ? perm[pe] : 0;
    const int j = idx_j[e];
    const short8* xp = (const short8*)(xs + (size_t)j * 256);
    const int q0 = kseg * 2;
    short8 fh0 = xp[q0    ];
    short8 fh1 = xp[q0 + 1];
    short8 fl0 = xp[16 + q0    ];
    short8 fl1 = xp[16 + q0 + 1];
    ahl[0*512 + (q0+0)*32 + (row ^ (q0+0))] = fh0;
    ahl[0*512 + (q0+1)*32 + (row ^ (q0+1))] = fh1;
    ahl[1*512 + (q0+0)*32 + (row ^ (q0+0))] = fl0;
    ahl[1*512 + (q0+1)*32 + (row ^ (q0+1))] = fl1;
  }
  if (t < 64){
    const int row = t >> 1, kseg = t & 1;
    const int pe = e0 + row;
    const int e = (pe < E) ? perm[pe] : 0;
    const float4* gp = (const float4*)(g + (size_t)e * 32 + kseg * 16);
    short8 fh0, fh1, fl0, fl1;
#pragma unroll
    for (int q = 0; q < 4; ++q){
      float4 f4 = gp[q];
      float vv[4] = {f4.x, f4.y, f4.z, f4.w};
#pragma unroll
      for (int uu = 0; uu < 4; ++uu){
        unsigned short hh, ll;
        split2(vv[uu], hh, ll);
        int i = q * 4 + uu;
        if (i < 8){ fh0[i]   = (short)hh; fl0[i]   = (short)ll; }
        else      { fh1[i-8] = (short)hh; fl1[i-8] = (short)ll; }
      }
    }
    const int q0 = kseg * 2;
    ghl[0*128 + (q0+0)*32 + (row ^ (q0+0))] = fh0;
    ghl[0*128 + (q0+1)*32 + (row ^ (q0+1))] = fh1;
    ghl[1*128 + (q0+0)*32 + (row ^ (q0+0))] = fl0;
    ghl[1*128 + (q0+1)*32 + (row ^ (q0+1))] = fl1;
  }
  if (t >= 64 && t < 96){
    int rr = t - 64, pe = e0 + rr;
    ii_s[rr] = (pe < E) ? idx_i[perm[pe]] : -1;
  }
  __syncthreads();

  f32x4 am[2][2], ag[2][2];
#pragma unroll
  for (int a = 0; a < 2; ++a)
#pragma unroll
    for (int b = 0; b < 2; ++b){
      am[a][b] = (f32x4){0.f, 0.f, 0.f, 0.f};
      ag[a][b] = (f32x4){0.f, 0.f, 0.f, 0.f};
    }

#pragma unroll
  for (int s = 0; s < 4; ++s){
    const int q = s * 4 + lq;
    short8 a0h = ahl[0*512 + q*32 + ((l15     ) ^ q)];
    short8 a0l = ahl[1*512 + q*32 + ((l15     ) ^ q)];
    short8 a1h = ahl[0*512 + q*32 + ((16 + l15) ^ q)];
    short8 a1l = ahl[1*512 + q*32 + ((16 + l15) ^ q)];
#pragma unroll
    for (int c = 0; c < 2; ++c){
      const int ct = w * 2 + c;
      short8 bh = wjf[((ct*4 + s)*2 + 0)*64 + lane];
      short8 bl = wjf[((ct*4 + s)*2 + 1)*64 + lane];
      am[0][c] = __builtin_amdgcn_mfma_f32_16x16x32_bf16(a0h, bh, am[0][c], 0, 0, 0);
      am[0][c] = __builtin_amdgcn_mfma_f32_16x16x32_bf16(a0h, bl, am[0][c], 0, 0, 0);
      am[0][c] = __builtin_amdgcn_mfma_f32_16x16x32_bf16(a0l, bh, am[0][c], 0, 0, 0);
      am[1][c] = __builtin_amdgcn_mfma_f32_16x16x32_bf16(a1h, bh, am[1][c], 0, 0, 0);
      am[1][c] = __builtin_amdgcn_mfma_f32_16x16x32_bf16(a1h, bl, am[1][c], 0, 0, 0);
      am[1][c] = __builtin_amdgcn_mfma_f32_16x16x32_bf16(a1l, bh, am[1][c], 0, 0, 0);
    }
  }
  {
    const int q = lq;
    short8 g0h = ghl[0*128 + q*32 + ((l15     ) ^ q)];
    short8 g0l = ghl[1*128 + q*32 + ((l15     ) ^ q)];
    short8 g1h = ghl[0*128 + q*32 + ((16 + l15) ^ q)];
    short8 g1l = ghl[1*128 + q*32 + ((16 + l15) ^ q)];
#pragma unroll
    for (int c = 0; c < 2; ++c){
      const int ct = w * 2 + c;
      short8 bh = wgf[(ct*2 + 0)*64 + lane];
      short8 bl = wgf[(ct*2 + 1)*64 + lane];
      ag[0][c] = __builtin_amdgcn_mfma_f32_16x16x32_bf16(g0h, bh, ag[0][c], 0, 0, 0);
      ag[0][c] = __builtin_amdgcn_mfma_f32_16x16x32_bf16(g0h, bl, ag[0][c], 0, 0, 0);
      ag[0][c] = __builtin_amdgcn_mfma_f32_16x16x32_bf16(g0l, bh, ag[0][c], 0, 0, 0);
      ag[1][c] = __builtin_amdgcn_mfma_f32_16x16x32_bf16(g1h, bh, ag[1][c], 0, 0, 0);
      ag[1][c] = __builtin_amdgcn_mfma_f32_16x16x32_bf16(g1h, bl, ag[1][c], 0, 0, 0);
      ag[1][c] = __builtin_amdgcn_mfma_f32_16x16x32_bf16(g1l, bh, ag[1][c], 0, 0, 0);
    }
  }

  // --- epilogue: vp -> transposed LDS, parallel segmented flush ---
  __syncthreads();   // all MFMA operand reads from ahl/ghl are done
#pragma unroll
  for (int c = 0; c < 2; ++c){
    const int col = (w * 2 + c) * 16 + l15;
    const float bjv = bj[col];
#pragma unroll
    for (int rt = 0; rt < 2; ++rt)
#pragma unroll
      for (int r = 0; r < 4; ++r){
        const int row = rt * 16 + lq * 4 + r;
        vp_s[col * 33 + row] = ssp(am[rt][c][r] + bjv) * ag[rt][c][r];
      }
  }
  __syncthreads();
  {
    const int col = t & 127;
    const int rbase = (t >> 7) * 16;
    float acc = 0.f;
    int curi = -1;
#pragma unroll
    for (int r = 0; r < 16; ++r){
      const int ii = ii_s[rbase + r];
      const float v = vp_s[col * 33 + rbase + r];
      if (ii == curi) acc += v;
      else {
        if (curi >= 0) atomicAdd(&vacc[(size_t)curi * 128 + col], acc);
        acc = v; curi = ii;
      }
    }
    if (curi >= 0) atomicAdd(&vacc[(size_t)curi * 128 + col], acc);
  }
}

// ---------- fused atom-side chain, v2: direct frag writes + double buffer ----------
// State (v,h,xa) in C-layout regs. Each GEMM: write split-bf16 A directly into
// frag-layout LDS buf^1 (16 ds_write_b16/lane), ONE barrier, MFMA from buf.
// Safe: writes to buf^1 follow own reads of buf; other waves' reads of buf^1
// (previous GEMM) completed before the last barrier (their writes to buf came
// after those reads, and the barrier ordered the writes).
// NOTE: vacc aliases out[0:N*128]; xs may alias the h-half (k_edge completes
// before k_chain; each k_chain block only writes rows it owns, after its reads).
__global__ __launch_bounds__(256) void k_chain(
    const float* __restrict__ x, const float* vacc,
    const short8* __restrict__ wcf,
    const float* __restrict__ bi, const float* __restrict__ bf_,
    const float* __restrict__ u,
    const float* __restrict__ bint, const float* __restrict__ batm,
    const float* __restrict__ bout,
    float* out, int N, int ni, int na, int no)
{
  __shared__ short8 ahl[2][1024];   // 2 x 16 KB frag buffers

  const int t    = threadIdx.x;
  const int lane = t & 63;
  const int w    = t >> 6;
  const int l15  = lane & 15;
  const int lq   = lane >> 4;
  const int r0   = blockIdx.x * 32;

  const int col0 = (w*2 + 0)*16 + l15;
  const int col1 = (w*2 + 1)*16 + l15;
  const int q0c = col0 >> 3, e0c = col0 & 7;   // frag coords for col0
  const int q1c = col1 >> 3, e1c = col1 & 7;   // frag coords for col1

  f32x4 am[2][2];
  int cur = 0;

  // write one bf16-split value at (local row, col-slot) into buffer b
  auto frag_put = [&](int b, int row, int qc, int ec, float v){
    unsigned short hh, ll;
    split2(v, hh, ll);
    unsigned short* base = (unsigned short*)&ahl[b][0];
    const int idx = (qc*32 + (row ^ qc))*8 + ec;
    base[idx]        = hh;    // hi plane: granules [0,512)
    base[4096 + idx] = ll;    // lo plane: granules [512,1024)
  };

  auto gemm = [&](const short8* __restrict__ wf){
    const short8* A = &ahl[cur][0];
#pragma unroll
    for (int a = 0; a < 2; ++a)
#pragma unroll
      for (int b = 0; b < 2; ++b) am[a][b] = (f32x4){0.f, 0.f, 0.f, 0.f};
#pragma unroll
    for (int s = 0; s < 4; ++s){
      const int q = s * 4 + lq;
      short8 a0h = A[0*512 + q*32 + ((l15     ) ^ q)];
      short8 a0l = A[1*512 + q*32 + ((l15     ) ^ q)];
      short8 a1h = A[0*512 + q*32 + ((16 + l15) ^ q)];
      short8 a1l = A[1*512 + q*32 + ((16 + l15) ^ q)];
#pragma unroll
      for (int c = 0; c < 2; ++c){
        const int ct = w * 2 + c;
        short8 bh = wf[((ct*4 + s)*2 + 0)*64 + lane];
        short8 bl = wf[((ct*4 + s)*2 + 1)*64 + lane];
        am[0][c] = __builtin_amdgcn_mfma_f32_16x16x32_bf16(a0h, bh, am[0][c], 0, 0, 0);
        am[0][c] = __builtin_amdgcn_mfma_f32_16x16x32_bf16(a0h, bl, am[0][c], 0, 0, 0);
        am[0][c] = __builtin_amdgcn_mfma_f32_16x16x32_bf16(a0l, bh, am[0][c], 0, 0, 0);
        am[1][c] = __builtin_amdgcn_mfma_f32_16x16x32_bf16(a1h, bh, am[1][c], 0, 0, 0);
        am[1][c] = __builtin_amdgcn_mfma_f32_16x16x32_bf16(a1h, bl, am[1][c], 0, 0, 0);
        am[1][c] = __builtin_amdgcn_mfma_f32_16x16x32_bf16(a1l, bh, am[1][c], 0, 0, 0);
      }
    }
  };

  // A = ssp(st), into buf^1; flip
  auto put_ssp_state = [&](float (&st)[2][2][4]){
    const int b = cur ^ 1;
#pragma unroll
    for (int rt = 0; rt < 2; ++rt)
#pragma unroll
      for (int r = 0; r < 4; ++r){
        const int row = rt*16 + lq*4 + r;
        frag_put(b, row, q0c, e0c, ssp(st[rt][0][r]));
        frag_put(b, row, q1c, e1c, ssp(st[rt][1][r]));
      }
    __syncthreads();
    cur = b;
  };
  // A = ssp(am + bias), into buf^1; flip
  auto put_ssp_amb = [&](float b0, float b1){
    const int b = cur ^ 1;
#pragma unroll
    for (int rt = 0; rt < 2; ++rt)
#pragma unroll
      for (int r = 0; r < 4; ++r){
        const int row = rt*16 + lq*4 + r;
        frag_put(b, row, q0c, e0c, ssp(am[rt][0][r] + b0));
        frag_put(b, row, q1c, e1c, ssp(am[rt][1][r] + b1));
      }
    __syncthreads();
    cur = b;
  };

  auto residual = [&](float (&st)[2][2][4], const short8* wf, const float* bvec){
    const float b0 = bvec[col0], b1 = bvec[col1];
    put_ssp_state(st);
    gemm(wf);                 // am = ssp(st) @ W
    put_ssp_amb(b0, b1);
    gemm(wf);                 // am = ssp(h1) @ W
#pragma unroll
    for (int rt = 0; rt < 2; ++rt)
#pragma unroll
      for (int r = 0; r < 4; ++r){
        st[rt][0][r] += am[rt][0][r] + b0;
        st[rt][1][r] += am[rt][1][r] + b1;
      }
  };

  // ---- init: xa = ssp(x) in C-layout regs; frags straight to buf0 ----
  float xar[2][2][4];
#pragma unroll
  for (int rt = 0; rt < 2; ++rt)
#pragma unroll
    for (int r = 0; r < 4; ++r){
      int row = r0 + rt*16 + lq*4 + r; if (row >= N) row = N - 1;
      const int lrow = rt*16 + lq*4 + r;
      float v0 = ssp(x[(size_t)row*128 + col0]);
      float v1 = ssp(x[(size_t)row*128 + col1]);
      xar[rt][0][r] = v0; xar[rt][1][r] = v1;
      frag_put(0, lrow, q0c, e0c, v0);
      frag_put(0, lrow, q1c, e1c, v1);
    }
  __syncthreads();

  // layer 0: v = vacc + ssp(xa @ Wi + bi)
  gemm(wcf + 0);
  float vst[2][2][4];
  {
    const float b0 = bi[col0], b1 = bi[col1];
#pragma unroll
    for (int rt = 0; rt < 2; ++rt)
#pragma unroll
      for (int r = 0; r < 4; ++r){
        int row = r0 + rt*16 + lq*4 + r; if (row >= N) row = N - 1;
        vst[rt][0][r] = vacc[(size_t)row*128 + col0] + ssp(am[rt][0][r] + b0);
        vst[rt][1][r] = vacc[(size_t)row*128 + col1] + ssp(am[rt][1][r] + b1);
      }
  }

  for (int kk = 0; kk < ni; ++kk)
    residual(vst, wcf + (size_t)(1 + kk) * 4096, bint + kk*128);

  // h = u*xa + ssp(v) @ Wf + bf
  put_ssp_state(vst);
  gemm(wcf + (size_t)(1 + ni) * 4096);
  float hst[2][2][4];
  {
    const float b0 = bf_[col0], b1 = bf_[col1];
    const float u0 = u[col0],   u1 = u[col1];
#pragma unroll
    for (int rt = 0; rt < 2; ++rt)
#pragma unroll
      for (int r = 0; r < 4; ++r){
        hst[rt][0][r] = u0 * xar[rt][0][r] + am[rt][0][r] + b0;
        hst[rt][1][r] = u1 * xar[rt][1][r] + am[rt][1][r] + b1;
      }
  }

  for (int kk = 0; kk < na; ++kk)
    residual(hst, wcf + (size_t)(2 + ni + kk) * 4096, batm + kk*128);

  // store h (second tuple element)
#pragma unroll
  for (int rt = 0; rt < 2; ++rt)
#pragma unroll
    for (int r = 0; r < 4; ++r){
      const int row = r0 + rt*16 + lq*4 + r;
      if (row < N){
        out[(size_t)N*128 + (size_t)row*128 + col0] = hst[rt][0][r];
        out[(size_t)N*128 + (size_t)row*128 + col1] = hst[rt][1][r];
      }
    }

  for (int kk = 0; kk < no; ++kk)
    residual(hst, wcf + (size_t)(2 + ni + na + kk) * 4096, bout + kk*128);

  // o = ssp(o): store first tuple element
#pragma unroll
  for (int rt = 0; rt < 2; ++rt)
#pragma unroll
    for (int r = 0; r < 4; ++r){
      const int row = r0 + rt*16 + lq*4 + r;
      if (row < N){
        out[(size_t)row*128 + col0] = ssp(hst[rt][0][r]);
        out[(size_t)row*128 + col1] = ssp(hst[rt][1][r]);
      }
    }
}

// ---------- launch ----------
extern "C" void kernel_launch(void* const* d_in, const int* in_sizes, int n_in,
                              void* d_out, int out_size, void* d_ws, size_t ws_size,
                              hipStream_t stream)
{
  const float* x    = (const float*)d_in[0];
  const float* g    = (const float*)d_in[1];
  const float* Wf   = (const float*)d_in[2];
  const float* bf_  = (const float*)d_in[3];
  const float* Wg   = (const float*)d_in[4];
  const float* Wj   = (const float*)d_in[5];
  const float* bj   = (const float*)d_in[6];
  const float* Wi   = (const float*)d_in[7];
  const float* bi   = (const float*)d_in[8];
  const float* u    = (const float*)d_in[9];
  const float* Wint = (const float*)d_in[10];
  const float* bint = (const float*)d_in[11];
  const float* Watm = (const float*)d_in[12];
  const float* batm = (const float*)d_in[13];
  const float* Wout = (const float*)d_in[14];
  const float* bout = (const float*)d_in[15];
  const int* idx_i  = (const int*)d_in[16];
  const int* idx_j  = (const int*)d_in[17];

  const int N  = in_sizes[0] / 128;
  const int E  = in_sizes[16];
  const int ni = in_sizes[10] / 16384;
  const int na = in_sizes[12] / 16384;
  const int no = in_sizes[14] / 16384;

  const int nmat = 3 + ni + na + no;

  // vacc aliases the o-half of d_out (consumed before o is written).
  float* vacc = (float*)d_out;
  short8* wsf = (short8*)d_ws;
  const short8* wjf = wsf;                       // slot 0
  const short8* wcf = wsf + (size_t)1 * 4096;    // slots 1..nmat-1 (chain)
  const short8* wgf = wsf + (size_t)nmat * 4096; // slot nmat (Wg)

  // d_ws layout after frags: cnt[N] (doubles as ofs), bsums[1024], perm[E], xs
  const size_t frag_bytes = (size_t)(nmat + 1) * 65536;
  int* cnt   = (int*)((char*)d_ws + frag_bytes);
  int* bsums = cnt + N;
  int* perm  = bsums + 1024;
  char* after = (char*)(perm + E);
  const size_t used = (size_t)(after - (char*)d_ws);
  const size_t xs_bytes = (size_t)N * 256 * sizeof(unsigned short);
  unsigned short* xs = (ws_size >= used + xs_bytes)
      ? (unsigned short*)after
      : (unsigned short*)((float*)d_out + (size_t)N * 128);

  const int nblk = (N + 2047) / 2048;

  hipMemsetAsync(vacc, 0, (size_t)N * 128 * sizeof(float), stream);
  hipMemsetAsync(cnt, 0, (size_t)N * sizeof(int), stream);
  k_xconv  <<<dim3((N*128/4 + 255)/256), dim3(256), 0, stream>>>(x, xs, N * 128);
  k_wconv  <<<dim3((nmat + 1) * 8), dim3(256), 0, stream>>>(Wj, Wg, Wi, Wf, Wint, Watm, Wout,
                                                            (unsigned short*)d_ws, ni, na, no);
  k_hist   <<<dim3((E + 255)/256), dim3(256), 0, stream>>>(idx_i, cnt, E);
  k_scan1  <<<dim3(nblk), dim3(256), 0, stream>>>(cnt, bsums, N);
  k_scan2  <<<dim3(1), dim3(64), 0, stream>>>(bsums, nblk);
  k_scan3  <<<dim3((N + 255)/256), dim3(256), 0, stream>>>(cnt, bsums, N);
  k_scatter<<<dim3((E + 255)/256), dim3(256), 0, stream>>>(idx_i, cnt, perm, E);
  k_edge   <<<dim3((E + 31)/32), dim3(256), 0, stream>>>(xs, g, idx_i, idx_j, perm,
                                                         wjf, wgf, bj, vacc, E);
  k_chain  <<<dim3((N + 31)/32), dim3(256), 0, stream>>>(x, vacc, wcf,
                                                         bi, bf_, u, bint, batm, bout,
                                                         (float*)d_out, N, ni, na, no);
}